// Round 1
// baseline (625.746 us; speedup 1.0000x reference)
//
#include <hip/hip_runtime.h>

#define HDIM 20
#define BLOCK 256
#define LPE 4   // lanes per element
#define UPL 5   // hidden units per lane

// LDS layouts:
//  lds_whh[1200]: ((s*5+u)*3 + type)*20 + i  = w_hh[(type*20 + 5s+u)*20 + (5s+i)%20]
//                 (k-index rotated by 5s so lane-local Hreg[i] = h[(5s+i)%20] lines up)
//  lds_c[240]:    (s*5+u)*12 + f : per-unit constants (combined biases, w_ih rows, w_l cols)
//  lds_bl[2]:     b_l

__global__ __launch_bounds__(BLOCK) void gru_decoder_kernel(
    const float* __restrict__ hidden,
    const float* __restrict__ w_ih,
    const float* __restrict__ w_hh,
    const float* __restrict__ b_ih,
    const float* __restrict__ b_hh,
    const float* __restrict__ w_l,
    const float* __restrict__ b_l,
    const int*  __restrict__ step_ptr,
    float* __restrict__ out,
    int B)
{
    __shared__ float lds_whh[1200];
    __shared__ float lds_c[240];
    __shared__ float lds_bl[2];

    const int tid = threadIdx.x;

    // ---- build rotated weight tables in LDS (once per block) ----
    for (int idx = tid; idx < 1200; idx += BLOCK) {
        int i    = idx % 20;
        int t2   = idx / 20;
        int type = t2 % 3;
        int t3   = t2 / 3;
        int u    = t3 % 5;
        int s    = t3 / 5;
        int j    = 5 * s + u;           // hidden unit this row feeds
        int row  = type * 20 + j;       // row in w_hh (r/z/n block)
        int k    = (5 * s + i) % 20;    // rotated k index
        lds_whh[idx] = w_hh[row * HDIM + k];
    }
    for (int idx = tid; idx < 240; idx += BLOCK) {
        int f = idx % 12;
        int u = (idx / 12) % 5;
        int s = idx / 60;
        int j = 5 * s + u;
        float v;
        switch (f) {
            case 0:  v = b_ih[j]      + b_hh[j];      break;  // combined r bias
            case 1:  v = b_ih[20 + j] + b_hh[20 + j]; break;  // combined z bias
            case 2:  v = b_ih[40 + j];                break;  // n input bias
            case 3:  v = b_hh[40 + j];                break;  // n hidden bias
            case 4:  v = w_ih[j * 2 + 0];             break;
            case 5:  v = w_ih[j * 2 + 1];             break;
            case 6:  v = w_ih[(20 + j) * 2 + 0];      break;
            case 7:  v = w_ih[(20 + j) * 2 + 1];      break;
            case 8:  v = w_ih[(40 + j) * 2 + 0];      break;
            case 9:  v = w_ih[(40 + j) * 2 + 1];      break;
            case 10: v = w_l[j];                      break;  // w_l[0][j]
            default: v = w_l[20 + j];                 break;  // w_l[1][j]
        }
        lds_c[idx] = v;
    }
    if (tid < 2) lds_bl[tid] = b_l[tid];
    __syncthreads();

    const int step = *step_ptr;
    const int s = tid & 3;                                  // slice within element
    const int e = (blockIdx.x * BLOCK + tid) >> 2;          // element index
    if (e >= B) return;                                     // B multiple of 16/wave -> wave-uniform

    // hoist per-unit constants to registers (60 VGPRs)
    float C[5][12];
    #pragma unroll
    for (int u = 0; u < 5; ++u)
        #pragma unroll
        for (int f = 0; f < 12; ++f)
            C[u][f] = lds_c[(s * 5 + u) * 12 + f];
    const float bl0 = lds_bl[0], bl1 = lds_bl[1];

    // initial hidden state, rotated: Hreg[i] = h0[e][(5s+i)%20]
    float Hreg[20];
    const float* hb = hidden + (size_t)e * HDIM;
    #pragma unroll
    for (int i = 0; i < 20; ++i)
        Hreg[i] = hb[(5 * s + i) % 20];

    float x0 = 0.f, x1 = 0.f;
    float* outp = out + (size_t)e * 2 * step;
    const float LOG2E = 1.4426950408889634f;
    const int wbase = s * 300;

    const int l  = tid & 63;
    const int lb = l & ~3;
    const int s1 = lb | ((l + 1) & 3);
    const int s2 = lb | ((l + 2) & 3);
    const int s3 = lb | ((l + 3) & 3);

    for (int t = 0; t < step; ++t) {
        float hnew[5];
        float py0 = 0.f, py1 = 0.f;
        #pragma unroll
        for (int u = 0; u < 5; ++u) {
            const float* w = &lds_whh[wbase + u * 60];
            float ar  = C[u][0] + x0 * C[u][4] + x1 * C[u][5];
            float az  = C[u][1] + x0 * C[u][6] + x1 * C[u][7];
            float ani = C[u][2] + x0 * C[u][8] + x1 * C[u][9];
            float anh = C[u][3];
            #pragma unroll
            for (int q = 0; q < 5; ++q) {
                float4 wr = *(const float4*)(w + q * 4);
                float4 wz = *(const float4*)(w + 20 + q * 4);
                float4 wn = *(const float4*)(w + 40 + q * 4);
                float h0v = Hreg[q * 4 + 0], h1v = Hreg[q * 4 + 1];
                float h2v = Hreg[q * 4 + 2], h3v = Hreg[q * 4 + 3];
                ar  += wr.x * h0v + wr.y * h1v + wr.z * h2v + wr.w * h3v;
                az  += wz.x * h0v + wz.y * h1v + wz.z * h2v + wz.w * h3v;
                anh += wn.x * h0v + wn.y * h1v + wn.z * h2v + wn.w * h3v;
            }
            // sigmoid(x) = rcp(1 + 2^(-x*log2e)); tanh(x) = 1 - 2*rcp(1 + 2^(2x*log2e))
            float r = __builtin_amdgcn_rcpf(1.f + __builtin_amdgcn_exp2f(-ar * LOG2E));
            float z = __builtin_amdgcn_rcpf(1.f + __builtin_amdgcn_exp2f(-az * LOG2E));
            float npre = ani + r * anh;
            float n = 1.f - 2.f * __builtin_amdgcn_rcpf(1.f + __builtin_amdgcn_exp2f(2.f * npre * LOG2E));
            float hv = n + z * (Hreg[u] - n);   // (1-z)*n + z*h
            hnew[u] = hv;
            py0 += hv * C[u][10];
            py1 += hv * C[u][11];
        }

        // y allreduce over the 4 slices (exact same association on all lanes)
        py0 += __shfl_xor(py0, 1);
        py0 += __shfl_xor(py0, 2);
        py1 += __shfl_xor(py1, 1);
        py1 += __shfl_xor(py1, 2);
        float y0 = py0 + bl0;
        float y1 = py1 + bl1;

        if (s == 0) {
            float2 st; st.x = y0; st.y = y1;
            *(float2*)(outp + 2 * (step - 1 - t)) = st;   // reversed time index
        }
        x0 = y0; x1 = y1;

        // h allgather: lane s+d's own units are Hreg positions 5d..5d+4 (rotation makes this uniform)
        #pragma unroll
        for (int i = 0; i < 5; ++i) {
            Hreg[5  + i] = __shfl(hnew[i], s1);
            Hreg[10 + i] = __shfl(hnew[i], s2);
            Hreg[15 + i] = __shfl(hnew[i], s3);
        }
        #pragma unroll
        for (int i = 0; i < 5; ++i) Hreg[i] = hnew[i];
    }
}

extern "C" void kernel_launch(void* const* d_in, const int* in_sizes, int n_in,
                              void* d_out, int out_size, void* d_ws, size_t ws_size,
                              hipStream_t stream) {
    const float* hidden = (const float*)d_in[0];
    const float* w_ih   = (const float*)d_in[1];
    const float* w_hh   = (const float*)d_in[2];
    const float* b_ih   = (const float*)d_in[3];
    const float* b_hh   = (const float*)d_in[4];
    const float* w_l    = (const float*)d_in[5];
    const float* b_l    = (const float*)d_in[6];
    const int*   step   = (const int*)d_in[7];
    float* out = (float*)d_out;

    int B = in_sizes[0] / HDIM;                 // hidden is (1, B, 20)
    int grid = (B * LPE + BLOCK - 1) / BLOCK;   // 4 lanes per element

    gru_decoder_kernel<<<grid, BLOCK, 0, stream>>>(
        hidden, w_ih, w_hh, b_ih, b_hh, w_l, b_l, step, out, B);
}

// Round 3
// 370.647 us; speedup vs baseline: 1.6883x; 1.6883x over previous
//
#include <hip/hip_runtime.h>

#define HDIM 20
#define BLOCK 256
#define LPE 4   // lanes per element; lane s owns units j = 4u+s, u=0..4

typedef __fp16 half2v __attribute__((ext_vector_type(2)));

static __device__ __forceinline__ float fdot2(half2v a, half2v b, float c) {
    return __builtin_amdgcn_fdot2(a, b, c, false);
}
static __device__ __forceinline__ half2v pk(float lo, float hi) {
    return __builtin_amdgcn_cvt_pkrtz(lo, hi);
}

__global__ __launch_bounds__(BLOCK, 2) void gru_decoder_kernel(
    const float* __restrict__ hidden,
    const float* __restrict__ w_ih,
    const float* __restrict__ w_hh,
    const float* __restrict__ b_ih,
    const float* __restrict__ b_hh,
    const float* __restrict__ w_l,
    const float* __restrict__ b_l,
    const int*  __restrict__ step_ptr,
    float* __restrict__ out,
    int B)
{
    const int tid = threadIdx.x;
    const int s = tid & 3;                            // slice within element
    const int e = (blockIdx.x * BLOCK + tid) >> 2;    // element index
    if (e >= B) return;                               // exact fit; wave-uniform

    const int step = *step_ptr;

    // ---- loop-invariant weights, packed fp16 in REGISTERS (no in-loop LDS) ----
    // Wp[u][g][p]: w_hh row (g*20 + 4u+s), k-pair p -> 150 VGPRs
    half2v Wp[5][3][10];
    half2v XW[5][3];                 // w_ih rows, IN=2 packed
    float  ar0[5], az0[5], ani0[5], anh0[5];
    float  wl0[5], wl1[5];
    #pragma unroll
    for (int u = 0; u < 5; ++u) {
        const int j = 4 * u + s;
        #pragma unroll
        for (int g = 0; g < 3; ++g) {
            const float* wr = w_hh + (g * 20 + j) * HDIM;
            #pragma unroll
            for (int p = 0; p < 10; ++p) {
                float2 w = *(const float2*)(wr + 2 * p);
                Wp[u][g][p] = pk(w.x, w.y);
            }
            float2 wi = *(const float2*)(w_ih + (g * 20 + j) * 2);
            XW[u][g] = pk(wi.x, wi.y);
        }
        ar0[u]  = b_ih[j]      + b_hh[j];
        az0[u]  = b_ih[20 + j] + b_hh[20 + j];
        ani0[u] = b_ih[40 + j];
        anh0[u] = b_hh[40 + j];
        wl0[u]  = w_l[j];
        wl1[u]  = w_l[20 + j];
    }
    const float bl0 = b_l[0], bl1 = b_l[1];

    // ---- state: own units fp32, full h as packed fp16 pairs ----
    float hprev[5];
    half2v Hpair[10];                // Hpair[p] = (h[2p], h[2p+1])
    {
        const float* hb = hidden + (size_t)e * HDIM;
        #pragma unroll
        for (int u = 0; u < 5; ++u) hprev[u] = hb[4 * u + s];
        #pragma unroll
        for (int p = 0; p < 10; ++p) {
            float2 h2 = *(const float2*)(hb + 2 * p);
            Hpair[p] = pk(h2.x, h2.y);
        }
    }

    half2v xp = pk(0.f, 0.f);        // packed (x0, x1)
    float* outp = out + (size_t)e * 2 * step;
    const float LOG2E = 1.4426950408889634f;

    const int lb = (tid & 63) & ~3;  // base lane of this element's quad

    for (int t = 0; t < step; ++t) {
        float hnew[5];
        float py0 = 0.f, py1 = 0.f;
        #pragma unroll
        for (int u = 0; u < 5; ++u) {
            // r gate: bias + x-part + h-part (two parallel sub-chains)
            float arA = fdot2(XW[u][0], xp, ar0[u]);
            float arB = fdot2(Wp[u][0][5], Hpair[5], 0.f);
            #pragma unroll
            for (int p = 0; p < 5; ++p) arA = fdot2(Wp[u][0][p], Hpair[p], arA);
            #pragma unroll
            for (int p = 6; p < 10; ++p) arB = fdot2(Wp[u][0][p], Hpair[p], arB);
            float ar = arA + arB;
            // z gate
            float azA = fdot2(XW[u][1], xp, az0[u]);
            float azB = fdot2(Wp[u][1][5], Hpair[5], 0.f);
            #pragma unroll
            for (int p = 0; p < 5; ++p) azA = fdot2(Wp[u][1][p], Hpair[p], azA);
            #pragma unroll
            for (int p = 6; p < 10; ++p) azB = fdot2(Wp[u][1][p], Hpair[p], azB);
            float az = azA + azB;
            // n gate: hidden part kept separate (multiplied by r)
            float anA = fdot2(Wp[u][2][0], Hpair[0], anh0[u]);
            float anB = fdot2(Wp[u][2][5], Hpair[5], 0.f);
            #pragma unroll
            for (int p = 1; p < 5; ++p) anA = fdot2(Wp[u][2][p], Hpair[p], anA);
            #pragma unroll
            for (int p = 6; p < 10; ++p) anB = fdot2(Wp[u][2][p], Hpair[p], anB);
            float anH = anA + anB;
            float anI = fdot2(XW[u][2], xp, ani0[u]);

            float r = __builtin_amdgcn_rcpf(1.f + __builtin_amdgcn_exp2f(-ar * LOG2E));
            float z = __builtin_amdgcn_rcpf(1.f + __builtin_amdgcn_exp2f(-az * LOG2E));
            float npre = anI + r * anH;
            float n = 1.f - 2.f * __builtin_amdgcn_rcpf(1.f + __builtin_amdgcn_exp2f(2.f * npre * LOG2E));
            float hv = n + z * (hprev[u] - n);   // (1-z)*n + z*h
            hnew[u] = hv;
            py0 += hv * wl0[u];
            py1 += hv * wl1[u];
        }

        // y allreduce over the 4 slices (butterfly -> identical value on all lanes)
        py0 += __shfl_xor(py0, 1);
        py0 += __shfl_xor(py0, 2);
        py1 += __shfl_xor(py1, 1);
        py1 += __shfl_xor(py1, 2);
        float y0 = py0 + bl0;
        float y1 = py1 + bl1;

        if (s == 0) {
            float2 st; st.x = y0; st.y = y1;
            *(float2*)(outp + 2 * (step - 1 - t)) = st;   // reversed time index
        }
        xp = pk(y0, y1);

        // h allgather: unit j = 4u + d lives on lane lb+d; rebuild packed pairs
        #pragma unroll
        for (int u = 0; u < 5; ++u) {
            float h0 = __shfl(hnew[u], lb + 0);
            float h1 = __shfl(hnew[u], lb + 1);
            float h2 = __shfl(hnew[u], lb + 2);
            float h3 = __shfl(hnew[u], lb + 3);
            Hpair[2 * u + 0] = pk(h0, h1);
            Hpair[2 * u + 1] = pk(h2, h3);
            hprev[u] = hnew[u];
        }
    }
}

extern "C" void kernel_launch(void* const* d_in, const int* in_sizes, int n_in,
                              void* d_out, int out_size, void* d_ws, size_t ws_size,
                              hipStream_t stream) {
    const float* hidden = (const float*)d_in[0];
    const float* w_ih   = (const float*)d_in[1];
    const float* w_hh   = (const float*)d_in[2];
    const float* b_ih   = (const float*)d_in[3];
    const float* b_hh   = (const float*)d_in[4];
    const float* w_l    = (const float*)d_in[5];
    const float* b_l    = (const float*)d_in[6];
    const int*   step   = (const int*)d_in[7];
    float* out = (float*)d_out;

    int B = in_sizes[0] / HDIM;                 // hidden is (1, B, 20)
    int grid = (B * LPE + BLOCK - 1) / BLOCK;   // 4 lanes per element

    gru_decoder_kernel<<<grid, BLOCK, 0, stream>>>(
        hidden, w_ih, w_hh, b_ih, b_hh, w_l, b_l, step, out, B);
}